// Round 1
// baseline (213.190 us; speedup 1.0000x reference)
//
#include <hip/hip_runtime.h>
#include <math.h>

// ---------------- problem constants ----------------
#define SEQL 1024
#define DIMC 256
#define NBATCH 8
#define NTOK 256
#define NST 16

// ---------------- ws layout (float offsets) ----------------
static const size_t OFF_XN     = 0;            // 2097152
static const size_t OFF_UF     = 2097152;      // 2097152
static const size_t OFF_UB     = 4194304;      // 2097152
static const size_t OFF_DF     = 6291456;      // 2097152
static const size_t OFF_DB     = 8388608;      // 2097152
static const size_t OFF_BFa    = 10485760;     // 131072
static const size_t OFF_CFa    = 10616832;     // 131072
static const size_t OFF_BBa    = 10747904;     // 131072
static const size_t OFF_CBa    = 10878976;     // 131072
static const size_t OFF_POOLX  = 11010048;     // 524288
static const size_t OFF_POOLXN = 11534336;     // 524288
static const size_t OFF_ZP     = 12058624;     // 524288
static const size_t OFF_Y1P    = 12582912;     // 524288
static const size_t OFF_Y2P    = 13107200;     // 524288
static const size_t OFF_WFT    = 13631488;     // 65536
static const size_t OFF_WBT    = 13697024;     // 65536
static const size_t OFF_P1T    = 13762560;     // 65536
static const size_t OFF_BFB    = 13828096;     // 256
static const size_t OFF_BBB    = 13828352;     // 256
static const size_t OFF_MASK   = 13828608;     // 256
static const size_t OFF_HOUT   = 13828864;     // 1048576
static const size_t OFF_PPROD  = 14877440;     // 1048576
static const size_t OFF_HIN    = 15926016;     // 1048576
// total 16974592 floats = ~67.9 MB

__device__ __forceinline__ float softplus_f(float x) {
    return fmaxf(x, 0.0f) + log1pf(__expf(-fabsf(x)));
}
__device__ __forceinline__ float silu_f(float x) {
    return x / (1.0f + __expf(-x));
}

// ---------------- prep: combined conv∘p2 weights ----------------
// Wc[c,i] = sum_o conv_w[c,o] * p2_w[o,i]; stored transposed WT[i*256+c].
// bias'[c] = sum_o conv_w[c,o]*p2_b[o] + conv_b[c]
__global__ __launch_bounds__(256) void combine_w_k(
    const float* __restrict__ cf_w, const float* __restrict__ cf_b,
    const float* __restrict__ cb_w, const float* __restrict__ cb_b,
    const float* __restrict__ p2w, const float* __restrict__ p2b,
    float* __restrict__ WfT, float* __restrict__ bf,
    float* __restrict__ WbT, float* __restrict__ bb)
{
    int dir = blockIdx.y;
    const float* CW = dir ? cb_w : cf_w;
    const float* CB = dir ? cb_b : cf_b;
    float* WT = dir ? WbT : WfT;
    float* BO = dir ? bb : bf;
    int c = blockIdx.x;
    int tid = threadIdx.x;
    __shared__ float row[256];
    __shared__ float red[256];
    row[tid] = CW[c * 256 + tid];
    __syncthreads();
    float acc = 0.0f;
    for (int j = 0; j < 256; j++) acc += row[j] * p2w[j * 256 + tid];
    WT[tid * 256 + c] = acc;
    red[tid] = row[tid] * p2b[tid];
    __syncthreads();
    for (int s = 128; s > 0; s >>= 1) {
        if (tid < s) red[tid] += red[tid + s];
        __syncthreads();
    }
    if (tid == 0) BO[c] = red[0] + CB[c];
}

__global__ __launch_bounds__(256) void transpose_k(const float* __restrict__ W,
                                                   float* __restrict__ WT)
{
    int k = blockIdx.x, n = threadIdx.x;
    WT[k * 256 + n] = W[n * 256 + k];
}

__global__ __launch_bounds__(256) void mask_k(float* __restrict__ mask)
{
    int t = threadIdx.x;
    float dx = (float)t - 128.0f;
    float wv = __expf(-0.5f * dx * dx / 4096.0f);   // sigma = 64 exactly
    __shared__ float red[256];
    red[t] = wv;
    __syncthreads();
    for (int s = 128; s > 0; s >>= 1) {
        if (t < s) red[t] += red[t + s];
        __syncthreads();
    }
    mask[t] = wv / red[0];
}

// ---------------- LayerNorm + adapool(x) + adapool(xn) ----------------
__global__ __launch_bounds__(256) void ln_pool_k(
    const float* __restrict__ x, const float* __restrict__ g, const float* __restrict__ be,
    float* __restrict__ xn, float* __restrict__ poolx, float* __restrict__ poolxn)
{
    int blk = blockIdx.x;           // b*256 + t
    int tid = threadIdx.x;
    int w = tid >> 6, lane = tid & 63;
    __shared__ float bufx[4][256];
    __shared__ float bufn[4][256];
    int row = blk * 4 + w;          // = b*1024 + 4t + w
    float4 v = *(const float4*)&x[(size_t)row * 256 + lane * 4];
    float s = v.x + v.y + v.z + v.w;
    #pragma unroll
    for (int m = 1; m < 64; m <<= 1) s += __shfl_xor(s, m);
    float mu = s * (1.0f / 256.0f);
    float cx = v.x - mu, cy = v.y - mu, cz = v.z - mu, cw = v.w - mu;
    float ss = cx * cx + cy * cy + cz * cz + cw * cw;
    #pragma unroll
    for (int m = 1; m < 64; m <<= 1) ss += __shfl_xor(ss, m);
    float rs = rsqrtf(ss * (1.0f / 256.0f) + 1e-5f);
    float4 g4 = *(const float4*)&g[lane * 4];
    float4 b4 = *(const float4*)&be[lane * 4];
    float4 o;
    o.x = cx * rs * g4.x + b4.x;
    o.y = cy * rs * g4.y + b4.y;
    o.z = cz * rs * g4.z + b4.z;
    o.w = cw * rs * g4.w + b4.w;
    *(float4*)&xn[(size_t)row * 256 + lane * 4] = o;
    *(float4*)&bufx[w][lane * 4] = v;
    *(float4*)&bufn[w][lane * 4] = o;
    __syncthreads();
    float px = (bufx[0][tid] + bufx[1][tid] + bufx[2][tid] + bufx[3][tid]) * 0.25f;
    float pn = (bufn[0][tid] + bufn[1][tid] + bufn[2][tid] + bufn[3][tid]) * 0.25f;
    poolx[(size_t)blk * 256 + tid] = px;
    poolxn[(size_t)blk * 256 + tid] = pn;
}

// ---------------- fp32 tiled GEMM: out = act(A @ W + bias) ----------------
// A: (M,256) row-major. WT: (256,256) [k][n]. Tile 128x128x32, 256 thr, 8x8 micro.
// ACT: 1 = softplus, 2 = silu
template <int ACT>
__global__ __launch_bounds__(256) void gemm_act_k(
    const float* __restrict__ A, int M,
    const float* __restrict__ WT0, const float* __restrict__ b0, float* __restrict__ out0,
    const float* __restrict__ WT1, const float* __restrict__ b1, float* __restrict__ out1)
{
    const float* WT = blockIdx.z ? WT1 : WT0;
    const float* bias = blockIdx.z ? b1 : b0;
    float* out = blockIdx.z ? out1 : out0;
    __shared__ float As[128 * 36];
    __shared__ float Ws[32 * 132];
    int tid = threadIdx.x;
    int bm = blockIdx.x, bn = blockIdx.y;
    int tr = tid >> 4, tc = tid & 15;
    float acc[8][8];
    #pragma unroll
    for (int i = 0; i < 8; i++)
        #pragma unroll
        for (int j = 0; j < 8; j++) acc[i][j] = 0.0f;

    for (int kt = 0; kt < 256; kt += 32) {
        #pragma unroll
        for (int i = 0; i < 4; i++) {
            int idx = tid + i * 256;
            int m = idx >> 3, kq = idx & 7;
            float4 v = *(const float4*)&A[(size_t)(bm * 128 + m) * 256 + kt + kq * 4];
            *(float4*)&As[m * 36 + kq * 4] = v;
        }
        #pragma unroll
        for (int i = 0; i < 4; i++) {
            int idx = tid + i * 256;
            int k = idx >> 5, n4 = idx & 31;
            float4 v = *(const float4*)&WT[(size_t)(kt + k) * 256 + bn * 128 + n4 * 4];
            *(float4*)&Ws[k * 132 + n4 * 4] = v;
        }
        __syncthreads();
        #pragma unroll
        for (int k = 0; k < 32; k++) {
            float a[8], w[8];
            #pragma unroll
            for (int i = 0; i < 8; i++) a[i] = As[(tr * 8 + i) * 36 + k];
            float4 wa = *(const float4*)&Ws[k * 132 + tc * 8];
            float4 wb = *(const float4*)&Ws[k * 132 + tc * 8 + 4];
            w[0] = wa.x; w[1] = wa.y; w[2] = wa.z; w[3] = wa.w;
            w[4] = wb.x; w[5] = wb.y; w[6] = wb.z; w[7] = wb.w;
            #pragma unroll
            for (int i = 0; i < 8; i++)
                #pragma unroll
                for (int j = 0; j < 8; j++) acc[i][j] += a[i] * w[j];
        }
        __syncthreads();
    }
    float bs[8];
    #pragma unroll
    for (int j = 0; j < 8; j++) bs[j] = bias[bn * 128 + tc * 8 + j];
    #pragma unroll
    for (int i = 0; i < 8; i++) {
        int row = bm * 128 + tr * 8 + i;
        float o[8];
        #pragma unroll
        for (int j = 0; j < 8; j++) {
            float v = acc[i][j] + bs[j];
            o[j] = (ACT == 1) ? softplus_f(v) : silu_f(v);
        }
        float4 oa = make_float4(o[0], o[1], o[2], o[3]);
        float4 ob = make_float4(o[4], o[5], o[6], o[7]);
        *(float4*)&out[(size_t)row * 256 + bn * 128 + tc * 8] = oa;
        *(float4*)&out[(size_t)row * 256 + bn * 128 + tc * 8 + 4] = ob;
    }
}

// ---------------- dbc = u @ dbc_w^T ; delta = softplus(dbc[:, :16] @ dt_w^T + dt_b) ----------------
__global__ __launch_bounds__(256) void dbc_delta_k(
    const float* __restrict__ u_f, const float* __restrict__ u_b,
    const float* __restrict__ dbcw_f, const float* __restrict__ dbcw_b,
    const float* __restrict__ dtw_f, const float* __restrict__ dtb_f,
    const float* __restrict__ dtw_b, const float* __restrict__ dtb_b,
    float* __restrict__ delta_f, float* __restrict__ delta_b,
    float* __restrict__ Bf, float* __restrict__ Bb,
    float* __restrict__ Cf, float* __restrict__ Cb)
{
    int dir = blockIdx.y;
    const float* U = dir ? u_b : u_f;
    const float* DW = dir ? dbcw_b : dbcw_f;
    const float* TW = dir ? dtw_b : dtw_f;
    const float* TB = dir ? dtb_b : dtb_f;
    float* DELTA = dir ? delta_b : delta_f;
    float* BOUT = dir ? Bb : Bf;
    float* COUT = dir ? Cb : Cf;

    int rb = blockIdx.x;       // rows rb*16 .. rb*16+15
    int tid = threadIdx.x;
    __shared__ float Us[16 * 260];
    __shared__ float dbcs[16 * 52];

    #pragma unroll
    for (int i = 0; i < 4; i++) {
        int idx = tid + i * 256;             // 1024 float4
        int r = idx >> 6, c4 = idx & 63;
        float4 v = *(const float4*)&U[(size_t)(rb * 16 + r) * 256 + c4 * 4];
        *(float4*)&Us[r * 260 + c4 * 4] = v;
    }
    __syncthreads();

    if (tid < 192) {
        int col = tid % 48;
        int rp = tid / 48;
        float acc0 = 0, acc1 = 0, acc2 = 0, acc3 = 0;
        const float* wrow = DW + (size_t)col * 256;
        for (int k = 0; k < 256; k += 4) {
            float4 w4 = *(const float4*)&wrow[k];
            float4 u0 = *(const float4*)&Us[(rp * 4 + 0) * 260 + k];
            float4 u1 = *(const float4*)&Us[(rp * 4 + 1) * 260 + k];
            float4 u2 = *(const float4*)&Us[(rp * 4 + 2) * 260 + k];
            float4 u3 = *(const float4*)&Us[(rp * 4 + 3) * 260 + k];
            acc0 += u0.x * w4.x + u0.y * w4.y + u0.z * w4.z + u0.w * w4.w;
            acc1 += u1.x * w4.x + u1.y * w4.y + u1.z * w4.z + u1.w * w4.w;
            acc2 += u2.x * w4.x + u2.y * w4.y + u2.z * w4.z + u2.w * w4.w;
            acc3 += u3.x * w4.x + u3.y * w4.y + u3.z * w4.z + u3.w * w4.w;
        }
        dbcs[(rp * 4 + 0) * 52 + col] = acc0;
        dbcs[(rp * 4 + 1) * 52 + col] = acc1;
        dbcs[(rp * 4 + 2) * 52 + col] = acc2;
        dbcs[(rp * 4 + 3) * 52 + col] = acc3;
    }
    __syncthreads();

    // delta: thread d = tid computes all 16 rows
    {
        int d = tid;
        float4 w0 = *(const float4*)&TW[d * 16];
        float4 w1 = *(const float4*)&TW[d * 16 + 4];
        float4 w2 = *(const float4*)&TW[d * 16 + 8];
        float4 w3 = *(const float4*)&TW[d * 16 + 12];
        float bsv = TB[d];
        #pragma unroll 4
        for (int jj = 0; jj < 16; jj++) {
            const float* dr = &dbcs[jj * 52];
            float4 x0 = *(const float4*)&dr[0];
            float4 x1 = *(const float4*)&dr[4];
            float4 x2 = *(const float4*)&dr[8];
            float4 x3 = *(const float4*)&dr[12];
            float s = bsv
                + x0.x * w0.x + x0.y * w0.y + x0.z * w0.z + x0.w * w0.w
                + x1.x * w1.x + x1.y * w1.y + x1.z * w1.z + x1.w * w1.w
                + x2.x * w2.x + x2.y * w2.y + x2.z * w2.z + x2.w * w2.w
                + x3.x * w3.x + x3.y * w3.y + x3.z * w3.z + x3.w * w3.w;
            DELTA[(size_t)(rb * 16 + jj) * 256 + d] = softplus_f(s);
        }
    }
    // B, C
    {
        int jj = tid >> 4, n = tid & 15;
        int rowg = rb * 16 + jj;
        BOUT[(size_t)rowg * 16 + n] = dbcs[jj * 52 + 16 + n];
        COUT[(size_t)rowg * 16 + n] = dbcs[jj * 52 + 32 + n];
    }
}

// ---------------- scan phase A: per-chunk (prod dA, h_out | h_in = 0) ----------------
__global__ __launch_bounds__(256) void scan_phaseA_k(
    const float* __restrict__ delta_f, const float* __restrict__ delta_b,
    const float* __restrict__ u_f, const float* __restrict__ u_b,
    const float* __restrict__ Bf, const float* __restrict__ Bb,
    const float* __restrict__ alog_f, const float* __restrict__ alog_b,
    float* __restrict__ hout, float* __restrict__ Pout)
{
    int chunk = blockIdx.x;   // 0..15
    int dblk = blockIdx.y;    // 0..15
    int z = blockIdx.z;       // dir*8 + b
    int dir = z >> 3, b = z & 7;
    int tid = threadIdx.x;
    int w = tid >> 6, lane = tid & 63;
    int g = lane >> 4, n = lane & 15;
    int d = dblk * 16 + w * 4 + g;

    const float* DELTA = dir ? delta_b : delta_f;
    const float* U = dir ? u_b : u_f;
    const float* Bm = dir ? Bb : Bf;
    const float* AL = dir ? alog_b : alog_f;

    float a_coef = -expf(AL[d * 16 + n]);

    int s0 = chunk * 64;
    int l0 = dir ? (1023 - s0) : s0;
    int lstep = dir ? -1 : 1;
    int base = b * 1024 + l0;
    const float* pd = DELTA + (size_t)base * 256 + d;
    const float* pu = U + (size_t)base * 256 + d;
    const float* pb = Bm + (size_t)base * 16 + n;
    int sd = lstep * 256, sb = lstep * 16;

    float h = 0.0f, P = 1.0f;
    #pragma unroll 4
    for (int j = 0; j < 64; j++) {
        float dlt = *pd;
        float uu = *pu;
        float bv = *pb;
        float dA = __expf(dlt * a_coef);
        h = dA * h + dlt * uu * bv;
        P *= dA;
        pd += sd; pu += sd; pb += sb;
    }
    int idx = ((z * 16 + chunk) * 256 + d) * 16 + n;
    hout[idx] = h;
    Pout[idx] = P;
}

// ---------------- scan phase B: sequential chunk combine ----------------
__global__ __launch_bounds__(256) void scan_phaseB_k(
    const float* __restrict__ hout, const float* __restrict__ Pout, float* __restrict__ hin)
{
    int gid = blockIdx.x * 256 + threadIdx.x;   // 65536
    int dn = gid & 4095;                        // d*16+n
    int z = gid >> 12;
    float h = 0.0f;
    #pragma unroll 4
    for (int c = 0; c < 16; c++) {
        int idx = (z * 16 + c) * 4096 + dn;
        hin[idx] = h;
        h = Pout[idx] * h + hout[idx];
    }
}

// ---------------- scan phase C: replay with correct h_in, pooled output ----------------
__global__ __launch_bounds__(256) void scan_phaseC_k(
    const float* __restrict__ delta_f, const float* __restrict__ delta_b,
    const float* __restrict__ u_f, const float* __restrict__ u_b,
    const float* __restrict__ Bf, const float* __restrict__ Bb,
    const float* __restrict__ Cf, const float* __restrict__ Cb,
    const float* __restrict__ alog_f, const float* __restrict__ alog_b,
    const float* __restrict__ Df, const float* __restrict__ Db,
    const float* __restrict__ hin,
    float* __restrict__ y1p, float* __restrict__ y2p)
{
    int chunk = blockIdx.x;
    int dblk = blockIdx.y;
    int z = blockIdx.z;
    int dir = z >> 3, b = z & 7;
    int tid = threadIdx.x;
    int w = tid >> 6, lane = tid & 63;
    int g = lane >> 4, n = lane & 15;
    int d = dblk * 16 + w * 4 + g;

    const float* DELTA = dir ? delta_b : delta_f;
    const float* U = dir ? u_b : u_f;
    const float* Bm = dir ? Bb : Bf;
    const float* Cm = dir ? Cb : Cf;
    const float* AL = dir ? alog_b : alog_f;
    const float* DD = dir ? Db : Df;
    float* YP = dir ? y2p : y1p;

    float a_coef = -expf(AL[d * 16 + n]);
    float Dd = DD[d];

    int s0 = chunk * 64;
    int l0 = dir ? (1023 - s0) : s0;
    int lstep = dir ? -1 : 1;
    int base = b * 1024 + l0;
    const float* pd = DELTA + (size_t)base * 256 + d;
    const float* pu = U + (size_t)base * 256 + d;
    const float* pb = Bm + (size_t)base * 16 + n;
    const float* pc = Cm + (size_t)base * 16 + n;
    int sd = lstep * 256, sb = lstep * 16;

    int idx = ((z * 16 + chunk) * 256 + d) * 16 + n;
    float h = hin[idx];

    for (int jb = 0; jb < 16; jb++) {
        float p = 0.0f, su = 0.0f;
        #pragma unroll
        for (int q = 0; q < 4; q++) {
            float dlt = *pd;
            float uu = *pu;
            float bv = *pb;
            float cv = *pc;
            float dA = __expf(dlt * a_coef);
            h = dA * h + dlt * uu * bv;
            p += h * cv;
            su += uu;
            pd += sd; pu += sd; pb += sb; pc += sb;
        }
        p += __shfl_xor(p, 1);
        p += __shfl_xor(p, 2);
        p += __shfl_xor(p, 4);
        p += __shfl_xor(p, 8);
        int l_last = l0 + lstep * (jb * 4 + 3);
        int t = l_last >> 2;
        if (n == 0) {
            YP[((size_t)(b * 256 + t)) * 256 + d] = (p + Dd * su) * 0.25f;
        }
    }
}

// ---------------- final: out = zp*(silu(y1p*mask)+silu(y2p*mask)) + skip ----------------
__global__ __launch_bounds__(256) void final_k(
    const float* __restrict__ zp, const float* __restrict__ y1p, const float* __restrict__ y2p,
    const float* __restrict__ poolx, const float* __restrict__ mask, float* __restrict__ out)
{
    int blk = blockIdx.x;
    int tid = threadIdx.x;
    int t = blk & 255;
    float m = mask[t];
    size_t idx = (size_t)blk * 256 + tid;
    float a = y1p[idx] * m;
    float c = y2p[idx] * m;
    out[idx] = zp[idx] * (silu_f(a) + silu_f(c)) + poolx[idx];
}

// ---------------- launcher ----------------
extern "C" void kernel_launch(void* const* d_in, const int* in_sizes, int n_in,
                              void* d_out, int out_size, void* d_ws, size_t ws_size,
                              hipStream_t stream)
{
    const float* x     = (const float*)d_in[0];
    const float* ln_g  = (const float*)d_in[1];
    const float* ln_b  = (const float*)d_in[2];
    const float* p1_w  = (const float*)d_in[3];
    const float* p1_b  = (const float*)d_in[4];
    const float* p2_w  = (const float*)d_in[5];
    const float* p2_b  = (const float*)d_in[6];
    const float* cf_w  = (const float*)d_in[7];
    const float* cf_b  = (const float*)d_in[8];
    const float* cb_w  = (const float*)d_in[9];
    const float* cb_b  = (const float*)d_in[10];
    const float* f_dbc = (const float*)d_in[11];
    const float* f_dtw = (const float*)d_in[12];
    const float* f_dtb = (const float*)d_in[13];
    const float* f_al  = (const float*)d_in[14];
    const float* f_D   = (const float*)d_in[15];
    const float* b_dbc = (const float*)d_in[16];
    const float* b_dtw = (const float*)d_in[17];
    const float* b_dtb = (const float*)d_in[18];
    const float* b_al  = (const float*)d_in[19];
    const float* b_D   = (const float*)d_in[20];

    float* ws = (float*)d_ws;
    float* xn     = ws + OFF_XN;
    float* u_f    = ws + OFF_UF;
    float* u_b    = ws + OFF_UB;
    float* delta_f= ws + OFF_DF;
    float* delta_b= ws + OFF_DB;
    float* Bf     = ws + OFF_BFa;
    float* Cf     = ws + OFF_CFa;
    float* Bb     = ws + OFF_BBa;
    float* Cb     = ws + OFF_CBa;
    float* poolx  = ws + OFF_POOLX;
    float* poolxn = ws + OFF_POOLXN;
    float* zp     = ws + OFF_ZP;
    float* y1p    = ws + OFF_Y1P;
    float* y2p    = ws + OFF_Y2P;
    float* WfT    = ws + OFF_WFT;
    float* WbT    = ws + OFF_WBT;
    float* p1T    = ws + OFF_P1T;
    float* bfb    = ws + OFF_BFB;
    float* bbb    = ws + OFF_BBB;
    float* maskw  = ws + OFF_MASK;
    float* hout   = ws + OFF_HOUT;
    float* Pprod  = ws + OFF_PPROD;
    float* hin    = ws + OFF_HIN;

    float* out = (float*)d_out;

    combine_w_k<<<dim3(256, 2), 256, 0, stream>>>(cf_w, cf_b, cb_w, cb_b, p2_w, p2_b,
                                                  WfT, bfb, WbT, bbb);
    transpose_k<<<256, 256, 0, stream>>>(p1_w, p1T);
    mask_k<<<1, 256, 0, stream>>>(maskw);
    ln_pool_k<<<2048, 256, 0, stream>>>(x, ln_g, ln_b, xn, poolx, poolxn);
    gemm_act_k<1><<<dim3(64, 2, 2), 256, 0, stream>>>(xn, 8192, WfT, bfb, u_f, WbT, bbb, u_b);
    gemm_act_k<2><<<dim3(16, 2, 1), 256, 0, stream>>>(poolxn, 2048, p1T, p1_b, zp, p1T, p1_b, zp);
    dbc_delta_k<<<dim3(512, 2), 256, 0, stream>>>(u_f, u_b, f_dbc, b_dbc,
                                                  f_dtw, f_dtb, b_dtw, b_dtb,
                                                  delta_f, delta_b, Bf, Bb, Cf, Cb);
    scan_phaseA_k<<<dim3(16, 16, 16), 256, 0, stream>>>(delta_f, delta_b, u_f, u_b,
                                                        Bf, Bb, f_al, b_al, hout, Pprod);
    scan_phaseB_k<<<256, 256, 0, stream>>>(hout, Pprod, hin);
    scan_phaseC_k<<<dim3(16, 16, 16), 256, 0, stream>>>(delta_f, delta_b, u_f, u_b,
                                                        Bf, Bb, Cf, Cb, f_al, b_al,
                                                        f_D, b_D, hin, y1p, y2p);
    final_k<<<2048, 256, 0, stream>>>(zp, y1p, y2p, poolx, maskw, out);
}

// Round 2
// 165.898 us; speedup vs baseline: 1.2851x; 1.2851x over previous
//
#include <hip/hip_runtime.h>
#include <math.h>

// ---------------- problem constants ----------------
#define SEQL 1024
#define DIMC 256
#define NBATCH 8
#define NTOK 256
#define NST 16

typedef unsigned short ushortT;
typedef unsigned int uintT;
using bf16x8 = __attribute__((ext_vector_type(8))) short;
using f32x4  = __attribute__((ext_vector_type(4))) float;

// ---------------- ws layout (float offsets) ----------------
static const size_t OFF_UF     = 0;            // 2097152 f32
static const size_t OFF_UB     = 2097152;      // 2097152
static const size_t OFF_DF     = 4194304;      // 2097152
static const size_t OFF_DB     = 6291456;      // 2097152
static const size_t OFF_BFa    = 8388608;      // 131072
static const size_t OFF_CFa    = 8519680;      // 131072
static const size_t OFF_BBa    = 8650752;      // 131072
static const size_t OFF_CBa    = 8781824;      // 131072
static const size_t OFF_POOLX  = 8912896;      // 524288
static const size_t OFF_ZP     = 9437184;      // 524288
static const size_t OFF_Y1P    = 9961472;      // 524288
static const size_t OFF_Y2P    = 10485760;     // 524288
static const size_t OFF_BFB    = 11010048;     // 256
static const size_t OFF_BBB    = 11010304;     // 256
static const size_t OFF_MASK   = 11010560;     // 256
static const size_t OFF_HOUT   = 11010816;     // 1048576
static const size_t OFF_PPROD  = 12059392;     // 1048576
static const size_t OFF_HIN    = 13107968;     // 1048576
// packed bf16 regions (sizes in floats; 2 ushorts per float slot)
static const size_t OFF_APK    = 14156544;     // 8192*256 bf16 = 1048576 f32 slots
static const size_t OFF_PPK    = 15205120;     // 2048*256 bf16 = 262144
static const size_t OFF_WFPK   = 15467264;     // 256*256 bf16 = 32768
static const size_t OFF_WBPK   = 15500032;     // 32768
static const size_t OFF_P1PK   = 15532800;     // 32768
// total 15565568 floats = ~62.3 MB

__device__ __forceinline__ float softplus_f(float x) {
    return fmaxf(x, 0.0f) + log1pf(__expf(-fabsf(x)));
}
__device__ __forceinline__ float silu_f(float x) {
    return x / (1.0f + __expf(-x));
}
__device__ __forceinline__ ushortT f2bf(float f) {
    uintT u = __float_as_uint(f);
    uintT r = (u + 0x7FFFu + ((u >> 16) & 1u)) >> 16;
    return (ushortT)r;
}
// fragment-pack index for element (k, n) of a (K=256, N=256-col-space) B operand,
// or (k, m) of A with m as "n". layout: [n16][kk][lane][j], lane = g*16 + (n&15),
// k = kk*32 + g*8 + j
__device__ __forceinline__ size_t pk_idx(int k, int n) {
    int n16 = n >> 4, kk = k >> 5, g = (k >> 3) & 3, j = k & 7;
    return ((((size_t)n16 * 8 + kk) * 64) + g * 16 + (n & 15)) * 8 + j;
}

// ---------------- prep: combined conv∘p2 weights, packed bf16 ----------------
__global__ __launch_bounds__(256) void combine_w_k(
    const float* __restrict__ cf_w, const float* __restrict__ cf_b,
    const float* __restrict__ cb_w, const float* __restrict__ cb_b,
    const float* __restrict__ p2w, const float* __restrict__ p2b,
    ushortT* __restrict__ Wfpk, float* __restrict__ bf,
    ushortT* __restrict__ Wbpk, float* __restrict__ bb)
{
    int dir = blockIdx.y;
    const float* CW = dir ? cb_w : cf_w;
    const float* CB = dir ? cb_b : cf_b;
    ushortT* WPK = dir ? Wbpk : Wfpk;
    float* BO = dir ? bb : bf;
    int c = blockIdx.x;            // output channel -> GEMM col n
    int tid = threadIdx.x;         // input channel  -> GEMM k
    __shared__ float row[256];
    __shared__ float red[256];
    row[tid] = CW[c * 256 + tid];
    __syncthreads();
    float acc = 0.0f;
    for (int j = 0; j < 256; j++) acc += row[j] * p2w[j * 256 + tid];
    WPK[pk_idx(tid, c)] = f2bf(acc);
    red[tid] = row[tid] * p2b[tid];
    __syncthreads();
    for (int s = 128; s > 0; s >>= 1) {
        if (tid < s) red[tid] += red[tid + s];
        __syncthreads();
    }
    if (tid == 0) BO[c] = red[0] + CB[c];
}

__global__ __launch_bounds__(256) void pack_p1_k(const float* __restrict__ p1w,
                                                 ushortT* __restrict__ P1pk)
{
    int c = blockIdx.x, i = threadIdx.x;   // n = c, k = i
    P1pk[pk_idx(i, c)] = f2bf(p1w[c * 256 + i]);
}

__global__ __launch_bounds__(256) void mask_k(float* __restrict__ mask)
{
    int t = threadIdx.x;
    float dx = (float)t - 128.0f;
    float wv = __expf(-0.5f * dx * dx / 4096.0f);   // sigma = 64 exactly
    __shared__ float red[256];
    red[t] = wv;
    __syncthreads();
    for (int s = 128; s > 0; s >>= 1) {
        if (t < s) red[t] += red[t + s];
        __syncthreads();
    }
    mask[t] = wv / red[0];
}

// ---------------- LayerNorm + adapool(x) + packed xn / packed pool(xn) ----------------
__global__ __launch_bounds__(256) void ln_pool_k(
    const float* __restrict__ x, const float* __restrict__ g, const float* __restrict__ be,
    ushortT* __restrict__ Apk, float* __restrict__ poolx, ushortT* __restrict__ Ppk)
{
    int blk = blockIdx.x;           // b*256 + t
    int tid = threadIdx.x;
    int w = tid >> 6, lane = tid & 63;
    __shared__ float bufx[4][256];
    __shared__ float bufn[4][256];
    int row = blk * 4 + w;          // = b*1024 + 4t + w
    float4 v = *(const float4*)&x[(size_t)row * 256 + lane * 4];
    float s = v.x + v.y + v.z + v.w;
    #pragma unroll
    for (int m = 1; m < 64; m <<= 1) s += __shfl_xor(s, m);
    float mu = s * (1.0f / 256.0f);
    float cx = v.x - mu, cy = v.y - mu, cz = v.z - mu, cw = v.w - mu;
    float ss = cx * cx + cy * cy + cz * cz + cw * cw;
    #pragma unroll
    for (int m = 1; m < 64; m <<= 1) ss += __shfl_xor(ss, m);
    float rs = rsqrtf(ss * (1.0f / 256.0f) + 1e-5f);
    float4 g4 = *(const float4*)&g[lane * 4];
    float4 b4 = *(const float4*)&be[lane * 4];
    float4 o;
    o.x = cx * rs * g4.x + b4.x;
    o.y = cy * rs * g4.y + b4.y;
    o.z = cz * rs * g4.z + b4.z;
    o.w = cw * rs * g4.w + b4.w;
    // packed bf16 write of xn: c0 = lane*4, 4 consecutive j in same (kk, g) group
    {
        int c0 = lane * 4;
        size_t pidx = pk_idx(c0, row);       // j0 = c0&7 in {0,4} -> 8B aligned
        ushort4 pv;
        pv.x = f2bf(o.x); pv.y = f2bf(o.y); pv.z = f2bf(o.z); pv.w = f2bf(o.w);
        *(ushort4*)&Apk[pidx] = pv;
    }
    *(float4*)&bufx[w][lane * 4] = v;
    *(float4*)&bufn[w][lane * 4] = o;
    __syncthreads();
    float px = (bufx[0][tid] + bufx[1][tid] + bufx[2][tid] + bufx[3][tid]) * 0.25f;
    float pn = (bufn[0][tid] + bufn[1][tid] + bufn[2][tid] + bufn[3][tid]) * 0.25f;
    poolx[(size_t)blk * 256 + tid] = px;
    Ppk[pk_idx(tid, blk)] = f2bf(pn);
}

// ---------------- packed-fragment MFMA GEMM: out = act(A @ W + bias) ----------------
// No LDS, no barriers. Each wave computes a 64x64 tile via 16 16x16x32 MFMAs per
// K-step (K=256 total, 8 steps). A: fragment-packed bf16 (M,256). B: fragment-packed
// bf16 (256,256), L2-resident. out: f32 row-major (M,256).
// ACT: 1 = softplus, 2 = silu
template <int ACT>
__global__ __launch_bounds__(256) void gemm_pk_k(
    const ushortT* __restrict__ Apk,
    const ushortT* __restrict__ Bpk0, const float* __restrict__ b0, float* __restrict__ out0,
    const ushortT* __restrict__ Bpk1, const float* __restrict__ b1, float* __restrict__ out1)
{
    const ushortT* Bpk = blockIdx.z ? Bpk1 : Bpk0;
    const float* bias = blockIdx.z ? b1 : b0;
    float* out = blockIdx.z ? out1 : out0;
    int tid = threadIdx.x;
    int w = tid >> 6, l = tid & 63;
    int mt = blockIdx.x * 4 + w;        // 64-row tile index
    int n16b = blockIdx.y * 4;          // base 16-col tile index

    f32x4 acc[4][4];
    #pragma unroll
    for (int i = 0; i < 4; i++)
        #pragma unroll
        for (int j = 0; j < 4; j++) acc[i][j] = (f32x4){0.f, 0.f, 0.f, 0.f};

    #pragma unroll
    for (int kk = 0; kk < 8; kk++) {
        bf16x8 a[4], b[4];
        #pragma unroll
        for (int i = 0; i < 4; i++)
            a[i] = *(const bf16x8*)&Apk[((((size_t)(mt * 4 + i)) * 8 + kk) * 64 + l) * 8];
        #pragma unroll
        for (int j = 0; j < 4; j++)
            b[j] = *(const bf16x8*)&Bpk[((((size_t)(n16b + j)) * 8 + kk) * 64 + l) * 8];
        #pragma unroll
        for (int i = 0; i < 4; i++)
            #pragma unroll
            for (int j = 0; j < 4; j++)
                acc[i][j] = __builtin_amdgcn_mfma_f32_16x16x32_bf16(a[i], b[j], acc[i][j], 0, 0, 0);
    }

    int cr = l & 15, rg = l >> 4;
    float bs[4];
    #pragma unroll
    for (int j = 0; j < 4; j++) bs[j] = bias[(n16b + j) * 16 + cr];
    #pragma unroll
    for (int i = 0; i < 4; i++) {
        #pragma unroll
        for (int j = 0; j < 4; j++) {
            #pragma unroll
            for (int r = 0; r < 4; r++) {
                int row = (mt * 4 + i) * 16 + rg * 4 + r;
                int col = (n16b + j) * 16 + cr;
                float v = acc[i][j][r] + bs[j];
                out[(size_t)row * 256 + col] = (ACT == 1) ? softplus_f(v) : silu_f(v);
            }
        }
    }
}

// ---------------- dbc = u @ dbc_w^T ; delta = softplus(dbc[:, :16] @ dt_w^T + dt_b) ----------------
__global__ __launch_bounds__(256) void dbc_delta_k(
    const float* __restrict__ u_f, const float* __restrict__ u_b,
    const float* __restrict__ dbcw_f, const float* __restrict__ dbcw_b,
    const float* __restrict__ dtw_f, const float* __restrict__ dtb_f,
    const float* __restrict__ dtw_b, const float* __restrict__ dtb_b,
    float* __restrict__ delta_f, float* __restrict__ delta_b,
    float* __restrict__ Bf, float* __restrict__ Bb,
    float* __restrict__ Cf, float* __restrict__ Cb)
{
    int dir = blockIdx.y;
    const float* U = dir ? u_b : u_f;
    const float* DW = dir ? dbcw_b : dbcw_f;
    const float* TW = dir ? dtw_b : dtw_f;
    const float* TB = dir ? dtb_b : dtb_f;
    float* DELTA = dir ? delta_b : delta_f;
    float* BOUT = dir ? Bb : Bf;
    float* COUT = dir ? Cb : Cf;

    int rb = blockIdx.x;       // rows rb*16 .. rb*16+15
    int tid = threadIdx.x;
    __shared__ float Us[16 * 260];
    __shared__ float dbcs[16 * 52];

    #pragma unroll
    for (int i = 0; i < 4; i++) {
        int idx = tid + i * 256;             // 1024 float4
        int r = idx >> 6, c4 = idx & 63;
        float4 v = *(const float4*)&U[(size_t)(rb * 16 + r) * 256 + c4 * 4];
        *(float4*)&Us[r * 260 + c4 * 4] = v;
    }
    __syncthreads();

    if (tid < 192) {
        int col = tid % 48;
        int rp = tid / 48;
        float acc0 = 0, acc1 = 0, acc2 = 0, acc3 = 0;
        const float* wrow = DW + (size_t)col * 256;
        for (int k = 0; k < 256; k += 4) {
            float4 w4 = *(const float4*)&wrow[k];
            float4 u0 = *(const float4*)&Us[(rp * 4 + 0) * 260 + k];
            float4 u1 = *(const float4*)&Us[(rp * 4 + 1) * 260 + k];
            float4 u2 = *(const float4*)&Us[(rp * 4 + 2) * 260 + k];
            float4 u3 = *(const float4*)&Us[(rp * 4 + 3) * 260 + k];
            acc0 += u0.x * w4.x + u0.y * w4.y + u0.z * w4.z + u0.w * w4.w;
            acc1 += u1.x * w4.x + u1.y * w4.y + u1.z * w4.z + u1.w * w4.w;
            acc2 += u2.x * w4.x + u2.y * w4.y + u2.z * w4.z + u2.w * w4.w;
            acc3 += u3.x * w4.x + u3.y * w4.y + u3.z * w4.z + u3.w * w4.w;
        }
        dbcs[(rp * 4 + 0) * 52 + col] = acc0;
        dbcs[(rp * 4 + 1) * 52 + col] = acc1;
        dbcs[(rp * 4 + 2) * 52 + col] = acc2;
        dbcs[(rp * 4 + 3) * 52 + col] = acc3;
    }
    __syncthreads();

    // delta: thread d = tid computes all 16 rows
    {
        int d = tid;
        float4 w0 = *(const float4*)&TW[d * 16];
        float4 w1 = *(const float4*)&TW[d * 16 + 4];
        float4 w2 = *(const float4*)&TW[d * 16 + 8];
        float4 w3 = *(const float4*)&TW[d * 16 + 12];
        float bsv = TB[d];
        #pragma unroll 4
        for (int jj = 0; jj < 16; jj++) {
            const float* dr = &dbcs[jj * 52];
            float4 x0 = *(const float4*)&dr[0];
            float4 x1 = *(const float4*)&dr[4];
            float4 x2 = *(const float4*)&dr[8];
            float4 x3 = *(const float4*)&dr[12];
            float s = bsv
                + x0.x * w0.x + x0.y * w0.y + x0.z * w0.z + x0.w * w0.w
                + x1.x * w1.x + x1.y * w1.y + x1.z * w1.z + x1.w * w1.w
                + x2.x * w2.x + x2.y * w2.y + x2.z * w2.z + x2.w * w2.w
                + x3.x * w3.x + x3.y * w3.y + x3.z * w3.z + x3.w * w3.w;
            DELTA[(size_t)(rb * 16 + jj) * 256 + d] = softplus_f(s);
        }
    }
    // B, C
    {
        int jj = tid >> 4, n = tid & 15;
        int rowg = rb * 16 + jj;
        BOUT[(size_t)rowg * 16 + n] = dbcs[jj * 52 + 16 + n];
        COUT[(size_t)rowg * 16 + n] = dbcs[jj * 52 + 32 + n];
    }
}

// ---------------- scan phase A: per-chunk (prod dA, h_out | h_in = 0) ----------------
__global__ __launch_bounds__(256) void scan_phaseA_k(
    const float* __restrict__ delta_f, const float* __restrict__ delta_b,
    const float* __restrict__ u_f, const float* __restrict__ u_b,
    const float* __restrict__ Bf, const float* __restrict__ Bb,
    const float* __restrict__ alog_f, const float* __restrict__ alog_b,
    float* __restrict__ hout, float* __restrict__ Pout)
{
    int chunk = blockIdx.x;   // 0..15
    int dblk = blockIdx.y;    // 0..15
    int z = blockIdx.z;       // dir*8 + b
    int dir = z >> 3, b = z & 7;
    int tid = threadIdx.x;
    int w = tid >> 6, lane = tid & 63;
    int g = lane >> 4, n = lane & 15;
    int d = dblk * 16 + w * 4 + g;

    const float* DELTA = dir ? delta_b : delta_f;
    const float* U = dir ? u_b : u_f;
    const float* Bm = dir ? Bb : Bf;
    const float* AL = dir ? alog_b : alog_f;

    float a_coef = -expf(AL[d * 16 + n]);

    int s0 = chunk * 64;
    int l0 = dir ? (1023 - s0) : s0;
    int lstep = dir ? -1 : 1;
    int base = b * 1024 + l0;
    const float* pd = DELTA + (size_t)base * 256 + d;
    const float* pu = U + (size_t)base * 256 + d;
    const float* pb = Bm + (size_t)base * 16 + n;
    int sd = lstep * 256, sb = lstep * 16;

    float h = 0.0f, P = 1.0f;
    #pragma unroll 4
    for (int j = 0; j < 64; j++) {
        float dlt = *pd;
        float uu = *pu;
        float bv = *pb;
        float dA = __expf(dlt * a_coef);
        h = dA * h + dlt * uu * bv;
        P *= dA;
        pd += sd; pu += sd; pb += sb;
    }
    int idx = ((z * 16 + chunk) * 256 + d) * 16 + n;
    hout[idx] = h;
    Pout[idx] = P;
}

// ---------------- scan phase B: sequential chunk combine ----------------
__global__ __launch_bounds__(256) void scan_phaseB_k(
    const float* __restrict__ hout, const float* __restrict__ Pout, float* __restrict__ hin)
{
    int gid = blockIdx.x * 256 + threadIdx.x;   // 65536
    int dn = gid & 4095;                        // d*16+n
    int z = gid >> 12;
    float h = 0.0f;
    #pragma unroll 4
    for (int c = 0; c < 16; c++) {
        int idx = (z * 16 + c) * 4096 + dn;
        hin[idx] = h;
        h = Pout[idx] * h + hout[idx];
    }
}

// ---------------- scan phase C: replay with correct h_in, pooled output ----------------
__global__ __launch_bounds__(256) void scan_phaseC_k(
    const float* __restrict__ delta_f, const float* __restrict__ delta_b,
    const float* __restrict__ u_f, const float* __restrict__ u_b,
    const float* __restrict__ Bf, const float* __restrict__ Bb,
    const float* __restrict__ Cf, const float* __restrict__ Cb,
    const float* __restrict__ alog_f, const float* __restrict__ alog_b,
    const float* __restrict__ Df, const float* __restrict__ Db,
    const float* __restrict__ hin,
    float* __restrict__ y1p, float* __restrict__ y2p)
{
    int chunk = blockIdx.x;
    int dblk = blockIdx.y;
    int z = blockIdx.z;
    int dir = z >> 3, b = z & 7;
    int tid = threadIdx.x;
    int w = tid >> 6, lane = tid & 63;
    int g = lane >> 4, n = lane & 15;
    int d = dblk * 16 + w * 4 + g;

    const float* DELTA = dir ? delta_b : delta_f;
    const float* U = dir ? u_b : u_f;
    const float* Bm = dir ? Bb : Bf;
    const float* Cm = dir ? Cb : Cf;
    const float* AL = dir ? alog_b : alog_f;
    const float* DD = dir ? Db : Df;
    float* YP = dir ? y2p : y1p;

    float a_coef = -expf(AL[d * 16 + n]);
    float Dd = DD[d];

    int s0 = chunk * 64;
    int l0 = dir ? (1023 - s0) : s0;
    int lstep = dir ? -1 : 1;
    int base = b * 1024 + l0;
    const float* pd = DELTA + (size_t)base * 256 + d;
    const float* pu = U + (size_t)base * 256 + d;
    const float* pb = Bm + (size_t)base * 16 + n;
    const float* pc = Cm + (size_t)base * 16 + n;
    int sd = lstep * 256, sb = lstep * 16;

    int idx = ((z * 16 + chunk) * 256 + d) * 16 + n;
    float h = hin[idx];

    for (int jb = 0; jb < 16; jb++) {
        float p = 0.0f, su = 0.0f;
        #pragma unroll
        for (int q = 0; q < 4; q++) {
            float dlt = *pd;
            float uu = *pu;
            float bv = *pb;
            float cv = *pc;
            float dA = __expf(dlt * a_coef);
            h = dA * h + dlt * uu * bv;
            p += h * cv;
            su += uu;
            pd += sd; pu += sd; pb += sb; pc += sb;
        }
        p += __shfl_xor(p, 1);
        p += __shfl_xor(p, 2);
        p += __shfl_xor(p, 4);
        p += __shfl_xor(p, 8);
        int l_last = l0 + lstep * (jb * 4 + 3);
        int t = l_last >> 2;
        if (n == 0) {
            YP[((size_t)(b * 256 + t)) * 256 + d] = (p + Dd * su) * 0.25f;
        }
    }
}

// ---------------- final: out = zp*(silu(y1p*mask)+silu(y2p*mask)) + skip ----------------
__global__ __launch_bounds__(256) void final_k(
    const float* __restrict__ zp, const float* __restrict__ y1p, const float* __restrict__ y2p,
    const float* __restrict__ poolx, const float* __restrict__ mask, float* __restrict__ out)
{
    int blk = blockIdx.x;
    int tid = threadIdx.x;
    int t = blk & 255;
    float m = mask[t];
    size_t idx = (size_t)blk * 256 + tid;
    float a = y1p[idx] * m;
    float c = y2p[idx] * m;
    out[idx] = zp[idx] * (silu_f(a) + silu_f(c)) + poolx[idx];
}

// ---------------- launcher ----------------
extern "C" void kernel_launch(void* const* d_in, const int* in_sizes, int n_in,
                              void* d_out, int out_size, void* d_ws, size_t ws_size,
                              hipStream_t stream)
{
    const float* x     = (const float*)d_in[0];
    const float* ln_g  = (const float*)d_in[1];
    const float* ln_b  = (const float*)d_in[2];
    const float* p1_w  = (const float*)d_in[3];
    const float* p1_b  = (const float*)d_in[4];
    const float* p2_w  = (const float*)d_in[5];
    const float* p2_b  = (const float*)d_in[6];
    const float* cf_w  = (const float*)d_in[7];
    const float* cf_b  = (const float*)d_in[8];
    const float* cb_w  = (const float*)d_in[9];
    const float* cb_b  = (const float*)d_in[10];
    const float* f_dbc = (const float*)d_in[11];
    const float* f_dtw = (const float*)d_in[12];
    const float* f_dtb = (const float*)d_in[13];
    const float* f_al  = (const float*)d_in[14];
    const float* f_D   = (const float*)d_in[15];
    const float* b_dbc = (const float*)d_in[16];
    const float* b_dtw = (const float*)d_in[17];
    const float* b_dtb = (const float*)d_in[18];
    const float* b_al  = (const float*)d_in[19];
    const float* b_D   = (const float*)d_in[20];

    float* ws = (float*)d_ws;
    float* u_f    = ws + OFF_UF;
    float* u_b    = ws + OFF_UB;
    float* delta_f= ws + OFF_DF;
    float* delta_b= ws + OFF_DB;
    float* Bf     = ws + OFF_BFa;
    float* Cf     = ws + OFF_CFa;
    float* Bb     = ws + OFF_BBa;
    float* Cb     = ws + OFF_CBa;
    float* poolx  = ws + OFF_POOLX;
    float* zp     = ws + OFF_ZP;
    float* y1p    = ws + OFF_Y1P;
    float* y2p    = ws + OFF_Y2P;
    float* bfb    = ws + OFF_BFB;
    float* bbb    = ws + OFF_BBB;
    float* maskw  = ws + OFF_MASK;
    float* hout   = ws + OFF_HOUT;
    float* Pprod  = ws + OFF_PPROD;
    float* hin    = ws + OFF_HIN;
    ushortT* Apk  = (ushortT*)(ws + OFF_APK);
    ushortT* Ppk  = (ushortT*)(ws + OFF_PPK);
    ushortT* Wfpk = (ushortT*)(ws + OFF_WFPK);
    ushortT* Wbpk = (ushortT*)(ws + OFF_WBPK);
    ushortT* P1pk = (ushortT*)(ws + OFF_P1PK);

    float* out = (float*)d_out;

    combine_w_k<<<dim3(256, 2), 256, 0, stream>>>(cf_w, cf_b, cb_w, cb_b, p2_w, p2_b,
                                                  Wfpk, bfb, Wbpk, bbb);
    pack_p1_k<<<256, 256, 0, stream>>>(p1_w, P1pk);
    mask_k<<<1, 256, 0, stream>>>(maskw);
    ln_pool_k<<<2048, 256, 0, stream>>>(x, ln_g, ln_b, Apk, poolx, Ppk);
    gemm_pk_k<1><<<dim3(32, 4, 2), 256, 0, stream>>>(Apk, Wfpk, bfb, u_f, Wbpk, bbb, u_b);
    gemm_pk_k<2><<<dim3(8, 4, 1), 256, 0, stream>>>(Ppk, P1pk, p1_b, zp, P1pk, p1_b, zp);
    dbc_delta_k<<<dim3(512, 2), 256, 0, stream>>>(u_f, u_b, f_dbc, b_dbc,
                                                  f_dtw, f_dtb, b_dtw, b_dtb,
                                                  delta_f, delta_b, Bf, Bb, Cf, Cb);
    scan_phaseA_k<<<dim3(16, 16, 16), 256, 0, stream>>>(delta_f, delta_b, u_f, u_b,
                                                        Bf, Bb, f_al, b_al, hout, Pprod);
    scan_phaseB_k<<<256, 256, 0, stream>>>(hout, Pprod, hin);
    scan_phaseC_k<<<dim3(16, 16, 16), 256, 0, stream>>>(delta_f, delta_b, u_f, u_b,
                                                        Bf, Bb, Cf, Cb, f_al, b_al,
                                                        f_D, b_D, hin, y1p, y2p);
    final_k<<<2048, 256, 0, stream>>>(zp, y1p, y2p, poolx, maskw, out);
}